// Round 7
// baseline (474.773 us; speedup 1.0000x reference)
//
#include <hip/hip_runtime.h>
#include <hip/hip_bf16.h>
#include <math.h>
#include <stdint.h>

typedef __bf16 bf16;
typedef __attribute__((ext_vector_type(4))) float floatx4;
typedef __attribute__((ext_vector_type(8))) bf16 bf16x8;
typedef __attribute__((ext_vector_type(4))) bf16 bf16x4;

#define LDS_ASYNC16(gptr, lptr)                                                \
  __builtin_amdgcn_global_load_lds(                                            \
      (const __attribute__((address_space(1))) void*)(gptr),                   \
      (__attribute__((address_space(3))) void*)(lptr), 16, 0, 0)

// ---------------- merge two fp32 partials ----------------
__global__ __launch_bounds__(256) void k_merge(const float* __restrict__ a,
                                               const float* __restrict__ b,
                                               float* __restrict__ out) {
  int i = (blockIdx.x * 256 + threadIdx.x) * 4;
  float4 va = *(const float4*)(a + i);
  float4 vb = *(const float4*)(b + i);
  float4 o;
  o.x = va.x + vb.x; o.y = va.y + vb.y; o.z = va.z + vb.z; o.w = va.w + vb.w;
  *(float4*)(out + i) = o;
}

// ---------------- fused prep: x cvt + wqkv transpose + wo transpose ---------
// Write phase uses 16B/lane (bf16x8) stores; block order is by-fast so 64
// consecutive blocks fill COMPLETE 8KB output rows (write locality + half the
// store instructions vs the 8B/lane version).
__device__ __forceinline__ void transpose_tile(const float* __restrict__ in,
                                               bf16* __restrict__ out, int K,
                                               int N, int bx, int by, int tid,
                                               float (*tile)[65]) {
  int k0 = by * 64, n0 = bx * 64;
  int cg = tid & 15, rr = tid >> 4;
#pragma unroll
  for (int p = 0; p < 4; ++p) {
    int r = rr + p * 16;
    float4 v = *(const float4*)(in + (size_t)(k0 + r) * N + n0 + cg * 4);
    tile[r][cg * 4 + 0] = v.x; tile[r][cg * 4 + 1] = v.y;
    tile[r][cg * 4 + 2] = v.z; tile[r][cg * 4 + 3] = v.w;
  }
  __syncthreads();
  int kc = tid & 7;                       // 8 k-chunks of 8
#pragma unroll
  for (int p = 0; p < 2; ++p) {
    int n = (tid >> 3) + p * 32;          // 32 rows per pass
    bf16x8 o;
#pragma unroll
    for (int e = 0; e < 8; ++e) o[e] = (bf16)tile[kc * 8 + e][n];
    *(bf16x8*)(out + (size_t)(n0 + n) * K + k0 + kc * 8) = o;
  }
}

__global__ __launch_bounds__(256) void k_prep(const float* __restrict__ x,
                                              const float* __restrict__ wqkv,
                                              const float* __restrict__ wo,
                                              bf16* __restrict__ x_bf,
                                              bf16* __restrict__ wqkvT,
                                              bf16* __restrict__ woT) {
  __shared__ float tile[64][65];
  int bid = blockIdx.x, tid = threadIdx.x;
  if (bid < 2048) {                       // x cvt: 8 floats/thread, 16B stores
    int i = (bid * 256 + tid) * 8;
    float4 a = *(const float4*)(x + i);
    float4 b = *(const float4*)(x + i + 4);
    bf16x8 o;
    o[0] = (bf16)a.x; o[1] = (bf16)a.y; o[2] = (bf16)a.z; o[3] = (bf16)a.w;
    o[4] = (bf16)b.x; o[5] = (bf16)b.y; o[6] = (bf16)b.z; o[7] = (bf16)b.w;
    *(bf16x8*)(x_bf + i) = o;
  } else if (bid < 8192) {
    int q = bid - 2048;                   // wqkv: 96(bx) x 64(by), by fast
    transpose_tile(wqkv, wqkvT, 4096, 6144, q >> 6, q & 63, tid, tile);
  } else {
    int q = bid - 8192;                   // wo: 64 x 64, by fast
    transpose_tile(wo, woT, 4096, 4096, q >> 6, q & 63, tid, tile);
  }
}

// ---------------- GEMM split-K: A[M][K] bf16 @ B[N][K] bf16 -----------------
// 128x128 tile, BK=32, LDS chunk-swizzled (round-0 proven structure).
__global__ __launch_bounds__(256) void k_gemm_bt(const bf16* __restrict__ A,
                                                 const bf16* __restrict__ B,
                                                 float* __restrict__ C,
                                                 int M, int N, int K, int ksplit) {
  __shared__ bf16 As[128 * 32];
  __shared__ bf16 Bs[128 * 32];
  int tid = threadIdx.x;
  int w = tid >> 6, lane = tid & 63;
  int lq = lane >> 4, l16 = lane & 15;
  int bm = blockIdx.y * 128, bn = blockIdx.x * 128;
  int wm = (w >> 1) * 64, wn = (w & 1) * 64;
  int kc = K / ksplit;
  int koff = blockIdx.z * kc;
  C += (size_t)blockIdx.z * M * N;
  floatx4 acc[4][4] = {};
  const bf16* Ab = A + (size_t)bm * K;
  const bf16* Bb = B + (size_t)bn * K;
  int srow = (lane >> 2);                               // 16 rows / instr
  int scol = (((lane & 3) ^ ((srow >> 1) & 3))) * 8;    // swizzled 16B chunk
  int sa = (l16 >> 1) & 3;                              // read-side swizzle

  for (int k0 = koff; k0 < koff + kc; k0 += 32) {
#pragma unroll
    for (int c = 0; c < 2; ++c) {
      int r = w * 32 + c * 16 + srow;
      LDS_ASYNC16(Ab + (size_t)r * K + k0 + scol, &As[(w * 32 + c * 16) * 32]);
      LDS_ASYNC16(Bb + (size_t)r * K + k0 + scol, &Bs[(w * 32 + c * 16) * 32]);
    }
    __syncthreads();
    bf16x8 af[4], bfr[4];
#pragma unroll
    for (int i = 0; i < 4; ++i)
      af[i] = *(const bf16x8*)&As[(wm + i * 16 + l16) * 32 + (lq ^ sa) * 8];
#pragma unroll
    for (int j = 0; j < 4; ++j)
      bfr[j] = *(const bf16x8*)&Bs[(wn + j * 16 + l16) * 32 + (lq ^ sa) * 8];
#pragma unroll
    for (int i = 0; i < 4; ++i)
#pragma unroll
      for (int j = 0; j < 4; ++j)
        acc[i][j] = __builtin_amdgcn_mfma_f32_16x16x32_bf16(af[i], bfr[j],
                                                            acc[i][j], 0, 0, 0);
    __syncthreads();
  }
  // C/D layout: col = lane&15, row = (lane>>4)*4 + reg  [m89-verified]
#pragma unroll
  for (int i = 0; i < 4; ++i)
#pragma unroll
    for (int j = 0; j < 4; ++j) {
      int m = bm + wm + i * 16 + lq * 4;
      int n = bn + wn + j * 16 + l16;
      float* cp = C + (size_t)m * N + n;
#pragma unroll
      for (int r = 0; r < 4; ++r) cp[(size_t)r * N] = acc[i][j][r];
    }
}

// ---------------- fused RoPE + assemble (one dispatch) ----------------------
// bid < 1024            : RoPE  (Q -> q_bf, new K rows -> kall)
// 1024 <= bid < 4096    : fill kall cache rows
// bid >= 4096           : build vT[hk][128][3072]
// The three parts are independent (disjoint outputs; all read GEMM1 partials).
__global__ __launch_bounds__(256) void k_rope_asm(
    const float* __restrict__ xp0, const float* __restrict__ xp1,
    bf16* __restrict__ qb, bf16* __restrict__ kall, bf16* __restrict__ vT,
    const float* __restrict__ ck, const float* __restrict__ cv,
    const int* __restrict__ seqstarts, const int* __restrict__ kvstarts,
    const int* __restrict__ cachestarts, const int* __restrict__ start_pos) {
  __shared__ float tile[64][130];
  int bid = blockIdx.x, tid = threadIdx.x;
  if (bid < 1024) {
    int t = bid;
    int s = 0;
    for (int i = 1; i < 4; ++i) if (seqstarts[i] <= t) s = i;
    int posn = t - seqstarts[s] + start_pos[s];
    float pos = (float)posn;
    int krow = kvstarts[s] + posn;          // destination row in kall
    for (int wk = tid; wk < 40 * 64; wk += 256) {
      int hh = wk >> 6, j = wk & 63;
      size_t idx = ((size_t)t * 48 + hh) * 128 + 2 * j;
      float2 a0 = *(const float2*)(xp0 + idx);
      float2 a1 = *(const float2*)(xp1 + idx);
      float x1 = a0.x + a1.x;
      float x2 = a0.y + a1.y;
      float invf = exp2f(-(float)j * 0.20762050593045935f);
      float ang = pos * invf;
      float sv, cv2;
      sincosf(ang, &sv, &cv2);
      float r1 = x1 * cv2 - x2 * sv;
      float r2 = x1 * sv + x2 * cv2;
      unsigned int u1 = (unsigned int)__builtin_bit_cast(unsigned short, (bf16)r1);
      unsigned int u2 = (unsigned int)__builtin_bit_cast(unsigned short, (bf16)r2);
      unsigned int pk = u1 | (u2 << 16);
      unsigned int* dst = (hh < 32)
          ? (unsigned int*)(qb + ((size_t)t * 32 + hh) * 128)
          : (unsigned int*)(kall + ((size_t)(hh - 32) * 3072 + krow) * 128);
      dst[j] = pk;
    }
    return;
  }
  int rb = bid - 1024;
  if (rb < 3072) {
    int p = rb;
    int b = 0;
    for (int i = 1; i < 4; ++i) if (kvstarts[i] <= p) b = i;
    int pkv = p - kvstarts[b];
    if (pkv >= start_pos[b]) return;   // new row: written by rope part
    int hk = tid >> 5, d4 = (tid & 31) * 4;
    int ci = cachestarts[b] + pkv;
    float4 v = *(const float4*)(ck + ((size_t)ci * 8 + hk) * 128 + d4);
    bf16x4 o;
    o[0] = (bf16)v.x; o[1] = (bf16)v.y; o[2] = (bf16)v.z; o[3] = (bf16)v.w;
    *(bf16x4*)(kall + ((size_t)hk * 3072 + p) * 128 + d4) = o;
    return;
  }
  int q = rb - 3072;                   // 0..383: hk = q/48, p-block = q%48
  int hk = q / 48, p0 = (q % 48) * 64;
  {
    int r = tid >> 2;
    int p = p0 + r;
    int b = 0;
    for (int i = 1; i < 4; ++i) if (kvstarts[i] <= p) b = i;
    int pkv = p - kvstarts[b];
    int f0 = (tid & 3) * 32;
    if (pkv >= start_pos[b]) {
      int tn = seqstarts[b] + pkv - start_pos[b];
      size_t base = (size_t)tn * 6144 + (40 + hk) * 128;
#pragma unroll
      for (int i = 0; i < 8; ++i) {
        float4 v0 = *(const float4*)(xp0 + base + f0 + i * 4);
        float4 v1 = *(const float4*)(xp1 + base + f0 + i * 4);
        tile[r][f0 + i * 4 + 0] = v0.x + v1.x;
        tile[r][f0 + i * 4 + 1] = v0.y + v1.y;
        tile[r][f0 + i * 4 + 2] = v0.z + v1.z;
        tile[r][f0 + i * 4 + 3] = v0.w + v1.w;
      }
    } else {
      int ci = cachestarts[b] + pkv;
      const float* src = cv + ((size_t)ci * 8 + hk) * 128;
#pragma unroll
      for (int i = 0; i < 8; ++i) {
        float4 v = *(const float4*)(src + f0 + i * 4);
        tile[r][f0 + i * 4 + 0] = v.x; tile[r][f0 + i * 4 + 1] = v.y;
        tile[r][f0 + i * 4 + 2] = v.z; tile[r][f0 + i * 4 + 3] = v.w;
      }
    }
  }
  __syncthreads();
  int d = tid >> 1, hf = tid & 1;
  bf16* dst = vT + ((size_t)hk * 128 + d) * 3072 + p0 + hf * 32;
#pragma unroll
  for (int qq = 0; qq < 4; ++qq) {
    bf16x8 o;
#pragma unroll
    for (int e = 0; e < 8; ++e) o[e] = (bf16)tile[hf * 32 + qq * 8 + e][d];
    *(bf16x8*)(dst + qq * 8) = o;
  }
}

// ---------------- flash attention (full KV per block, direct output) --------
// 1D grid of 512; second half uses REVERSED qbi order so the two blocks that
// land on the same CU (round-robin) get complementary (heavy,light) KV loads.
__global__ __launch_bounds__(256) void k_attn(
    const bf16* __restrict__ qb, const bf16* __restrict__ kall,
    const bf16* __restrict__ vT, bf16* __restrict__ aout,
    const int* __restrict__ seqstarts, const int* __restrict__ kvstarts,
    const int* __restrict__ start_pos) {
  __shared__ bf16 Ks[64 * 128];
  __shared__ bf16 Vs[128 * 64];
  __shared__ bf16 Ps[64 * 64];
  int bid = blockIdx.x;
  int half = bid >> 8, idx = bid & 255;
  int h = half * 16 + (idx >> 4);
  int qbi = half ? (idx & 15) : 15 - (idx & 15);
  int hk = h >> 2;
  int t0 = qbi * 64;
  int s = 0;
  for (int i = 1; i < 4; ++i) if (seqstarts[i] <= t0) s = i;
  int posbase = t0 - seqstarts[s] + start_pos[s];  // pos of query row 0
  int kv0 = kvstarts[s];
  int nkv = posbase + 64;              // keys needed (multiple of 64)
  int tid = threadIdx.x, w = tid >> 6, lane = tid & 63;
  int lq = lane >> 4, l16 = lane & 15;

  // Q fragments straight to registers (row = w*16+l16, chunk = kk*4+lq)
  bf16x8 qa[4];
#pragma unroll
  for (int kk = 0; kk < 4; ++kk)
    qa[kk] = *(const bf16x8*)(qb + (((size_t)(t0 + w * 16 + l16) * 32 + h) * 128 +
                                    kk * 32 + lq * 8));

  int krow = lane >> 4;
  int vrow = lane >> 3;
  int vchunk = ((lane & 7) ^ (vrow & 7));
  int sw8 = l16 & 7;

  float m_r[4], l_r[4];
  floatx4 oacc[8] = {};
#pragma unroll
  for (int rg = 0; rg < 4; ++rg) { m_r[rg] = -3.0e38f; l_r[rg] = 0.f; }
  const float scale = 0.08838834764831845f;

  for (int p0 = 0; p0 < nkv; p0 += 64) {
#pragma unroll
    for (int c = 0; c < 4; ++c) {
      int base_r = w * 16 + c * 4;                  // wave-uniform
      int r = base_r + krow;
      int gch = (lane & 15) ^ ((c * 4 + krow) & 15);
      LDS_ASYNC16(kall + (((size_t)hk * 3072 + kv0 + p0 + r) * 128 + gch * 8),
                  &Ks[base_r * 128]);
    }
#pragma unroll
    for (int c = 0; c < 4; ++c) {
      int base_d = w * 32 + c * 8;                  // wave-uniform
      int d = base_d + vrow;
      LDS_ASYNC16(vT + (((size_t)hk * 128 + d) * 3072 + kv0 + p0 + vchunk * 8),
                  &Vs[base_d * 64]);
    }
    __syncthreads();

    // S = Q K^T : wave w owns 16 query rows [w*16, w*16+16)
    floatx4 sacc[4] = {};
#pragma unroll
    for (int kk = 0; kk < 4; ++kk)
#pragma unroll
      for (int j = 0; j < 4; ++j) {
        bf16x8 kb = *(const bf16x8*)&Ks[(j * 16 + l16) * 128 +
                                        ((kk * 4 + lq) ^ l16) * 8];
        sacc[j] = __builtin_amdgcn_mfma_f32_16x16x32_bf16(qa[kk], kb, sacc[j], 0, 0, 0);
      }

    // online softmax; lane holds S[row=lq*4+rg][col=j*16+l16]
#pragma unroll
    for (int rg = 0; rg < 4; ++rg) {
      int qpos = posbase + w * 16 + lq * 4 + rg;
      float sv[4];
      float rmax = -3.0e38f;
#pragma unroll
      for (int j = 0; j < 4; ++j) {
        int pkv = p0 + j * 16 + l16;
        sv[j] = (pkv <= qpos) ? sacc[j][rg] * scale : -3.0e38f;
        rmax = fmaxf(rmax, sv[j]);
      }
#pragma unroll
      for (int off = 1; off < 16; off <<= 1)
        rmax = fmaxf(rmax, __shfl_xor(rmax, off, 64));
      float mnew = fmaxf(m_r[rg], rmax);
      float alpha = __expf(m_r[rg] - mnew);
      m_r[rg] = mnew;
      int prow = w * 16 + lq * 4 + rg;
      int pswz = (lq * 4 + rg) & 7;
      float psum = 0.f;
#pragma unroll
      for (int j = 0; j < 4; ++j) {
        float pv = __expf(sv[j] - mnew);
        psum += pv;
        int chunk = (j * 2 + (l16 >> 3)) ^ pswz;
        Ps[prow * 64 + chunk * 8 + (l16 & 7)] = (bf16)pv;
      }
#pragma unroll
      for (int off = 1; off < 16; off <<= 1) psum += __shfl_xor(psum, off, 64);
      l_r[rg] = l_r[rg] * alpha + psum;
#pragma unroll
      for (int nt = 0; nt < 8; ++nt) oacc[nt][rg] *= alpha;
    }

    // O += P V  (P rows of wave w only read by wave w -> no barrier needed)
#pragma unroll
    for (int kk = 0; kk < 2; ++kk) {
      bf16x8 pa = *(const bf16x8*)&Ps[(w * 16 + l16) * 64 +
                                      ((kk * 4 + lq) ^ sw8) * 8];
#pragma unroll
      for (int nt = 0; nt < 8; ++nt) {
        bf16x8 vb = *(const bf16x8*)&Vs[(nt * 16 + l16) * 64 +
                                        ((kk * 4 + lq) ^ sw8) * 8];
        oacc[nt] = __builtin_amdgcn_mfma_f32_16x16x32_bf16(pa, vb, oacc[nt], 0, 0, 0);
      }
    }
    __syncthreads();
  }

  // epilogue: normalize and write bf16 output directly
#pragma unroll
  for (int rg = 0; rg < 4; ++rg) {
    int row = w * 16 + lq * 4 + rg;
    float inv = 1.0f / l_r[rg];
    bf16* dst = aout + (size_t)(t0 + row) * 4096 + h * 128;
#pragma unroll
    for (int nt = 0; nt < 8; ++nt)
      dst[nt * 16 + l16] = (bf16)(oacc[nt][rg] * inv);
  }
}

// ---------------- host launcher ----------------
extern "C" void kernel_launch(void* const* d_in, const int* in_sizes, int n_in,
                              void* d_out, int out_size, void* d_ws, size_t ws_size,
                              hipStream_t stream) {
  const float* x = (const float*)d_in[0];
  const float* wqkv = (const float*)d_in[1];
  const float* wo = (const float*)d_in[2];
  const float* kv = (const float*)d_in[3];
  const int* seqstarts = (const int*)d_in[4];
  const int* kvstarts = (const int*)d_in[5];
  const int* cachestarts = (const int*)d_in[6];
  const int* start_pos = (const int*)d_in[7];
  float* out = (float*)d_out;

  char* base = (char*)d_ws;
  size_t off = 0;
  auto carve = [&](size_t bytes) {
    void* r = base + off;
    off += (bytes + 255) & ~(size_t)255;
    return r;
  };
  bf16* x_bf    = (bf16*)carve(1024ull * 4096 * 2);
  bf16* wqkvT   = (bf16*)carve(6144ull * 4096 * 2);
  bf16* woT     = (bf16*)carve(4096ull * 4096 * 2);
  float* xqkv   = (float*)carve(2ull * 1024 * 6144 * 4);  // 2 split-K partials
  bf16* q_bf    = (bf16*)carve(1024ull * 32 * 128 * 2);
  bf16* k_all   = (bf16*)carve(8ull * 3072 * 128 * 2);
  bf16* vT_all  = (bf16*)carve(8ull * 128 * 3072 * 2);
  bf16* attn_bf = (bf16*)carve(1024ull * 4096 * 2);
  // GEMM2 split-K partials alias wqkvT (48 MB >= 2*16.8 MB); wqkvT is dead
  // after GEMM1.  All consumers are stream-ordered.
  float* outp = (float*)wqkvT;

  float* xqkv1 = xqkv + 1024ull * 6144;
  const float* cache_v = kv + 8192ull * 8 * 128;  // kv_cache[0,1]

  // 1: fused cvt + weight transposes (16B stores, by-fast order)
  k_prep<<<12288, 256, 0, stream>>>(x, wqkv, wo, x_bf, wqkvT, woT);
  // 2: GEMM1 (split-K 2, partials summed downstream)
  k_gemm_bt<<<dim3(48, 8, 2), 256, 0, stream>>>(x_bf, wqkvT, xqkv, 1024, 6144,
                                                4096, 2);
  // 3: fused RoPE + K-cache fill + V transpose assemble
  k_rope_asm<<<4480, 256, 0, stream>>>(xqkv, xqkv1, q_bf, k_all, vT_all, kv,
                                       cache_v, seqstarts, kvstarts,
                                       cachestarts, start_pos);
  // 4: attention, full KV per block, balanced qbi pairing
  k_attn<<<512, 256, 0, stream>>>(q_bf, k_all, vT_all, attn_bf,
                                  seqstarts, kvstarts, start_pos);
  // 5: GEMM2 (split-K 2)
  k_gemm_bt<<<dim3(32, 8, 2), 256, 0, stream>>>(attn_bf, woT, outp, 1024, 4096,
                                                4096, 2);
  // 6: sum GEMM2 partials
  k_merge<<<4096, 256, 0, stream>>>(outp, outp + 1024ull * 4096, out);
}